// Round 1
// baseline (496.377 us; speedup 1.0000x reference)
//
#include <hip/hip_runtime.h>

// KruskalLinearLayer: y[n,abc] = sum_r g0[a,r]g1[b,r]g2[c,r] * s[n,r] + bias
//   s[n,r] = sum_{d,e,f} g3[d,r]g4[e,r]g5[f,r] * x[n,def]
//   g_m = f_m @ c_m   (16x8 @ 8x16 = 16x16)
// One wave (64 lanes) per batch row. Lane owns 4 contiguous columns
// (ef = lane*4+j on input, bc = lane*4+j on output). Memory-bound:
// 128 MB total traffic -> ~20 us floor.

#define WAVES_PER_BLOCK 4

__global__ __launch_bounds__(256, 4)
void kruskal_kernel(const float* __restrict__ x,
                    const float* __restrict__ c0, const float* __restrict__ c1,
                    const float* __restrict__ c2, const float* __restrict__ c3,
                    const float* __restrict__ c4, const float* __restrict__ c5,
                    const float* __restrict__ f0, const float* __restrict__ f1,
                    const float* __restrict__ f2, const float* __restrict__ f3,
                    const float* __restrict__ f4, const float* __restrict__ f5,
                    const float* __restrict__ bias,
                    float* __restrict__ out,
                    int N)
{
    // gt[m][r][idx] = g_m[idx][r]  (transposed so per-r rows are contiguous)
    __shared__ __align__(16) float gt[6 * 256];
    __shared__ __align__(16) float sb[4096];   // bias staged in LDS

    const int tid = threadIdx.x;

    // ---- per-block precompute: g_m = f_m @ c_m into LDS (transposed) ----
    {
        const float* F[6] = {f0, f1, f2, f3, f4, f5};
        const float* C[6] = {c0, c1, c2, c3, c4, c5};
        const int r = tid >> 4;   // 0..15
        const int a = tid & 15;   // 0..15
#pragma unroll
        for (int m = 0; m < 6; ++m) {
            const float* Fm = F[m];
            const float* Cm = C[m];
            float acc = 0.f;
#pragma unroll
            for (int k = 0; k < 8; ++k)
                acc += Fm[a * 8 + k] * Cm[k * 16 + r];
            gt[m * 256 + tid] = acc;   // = gt[m][r][a]
        }
    }
#pragma unroll
    for (int t = 0; t < 16; ++t)
        sb[t * 256 + tid] = bias[t * 256 + tid];
    __syncthreads();

    const int lane   = tid & 63;
    const int waveId = tid >> 6;
    const int eb     = lane >> 2;        // e (phase 1) == b (phase 2)
    const int fcb    = (lane & 3) * 4;   // f base (phase 1) == c base (phase 2)

    const int totalWaves = gridDim.x * WAVES_PER_BLOCK;

    for (int n = blockIdx.x * WAVES_PER_BLOCK + waveId; n < N; n += totalWaves) {
        const float* xn = x + (size_t)n * 4096;

        // ---- load lane's 64 x values: x[d][ef], ef = lane*4 + j ----
        float4 xv[16];
#pragma unroll
        for (int d = 0; d < 16; ++d)
            xv[d] = *(const float4*)(xn + d * 256 + lane * 4);

        // ---- phase 1: per-lane partial s[r] ----
        float s[16];
#pragma unroll
        for (int r = 0; r < 16; ++r) {
            const float* g3r = &gt[3 * 256 + r * 16];
            const float* g4r = &gt[4 * 256 + r * 16];
            const float* g5r = &gt[5 * 256 + r * 16];
            float4 t = {0.f, 0.f, 0.f, 0.f};
#pragma unroll
            for (int d = 0; d < 16; ++d) {
                const float g = g3r[d];
                t.x += g * xv[d].x;
                t.y += g * xv[d].y;
                t.z += g * xv[d].z;
                t.w += g * xv[d].w;
            }
            const float4 g5v = *(const float4*)(g5r + fcb);
            const float p = t.x * g5v.x + t.y * g5v.y + t.z * g5v.z + t.w * g5v.w;
            s[r] = p * g4r[eb];
        }

        // ---- wave-wide reduction of each s[r] across 64 lanes ----
#pragma unroll
        for (int r = 0; r < 16; ++r) {
            float v = s[r];
            v += __shfl_xor(v, 1, 64);
            v += __shfl_xor(v, 2, 64);
            v += __shfl_xor(v, 4, 64);
            v += __shfl_xor(v, 8, 64);
            v += __shfl_xor(v, 16, 64);
            v += __shfl_xor(v, 32, 64);
            s[r] = v;
        }

        // ---- phase 2: y[a][bc] = sum_r g0[a,r] * (g1[b,r] g2[c,r] s[r]) ----
        float4 acc[16];
#pragma unroll
        for (int a = 0; a < 16; ++a) acc[a] = {0.f, 0.f, 0.f, 0.f};
#pragma unroll
        for (int r = 0; r < 16; ++r) {
            const float* g0r = &gt[0 * 256 + r * 16];
            const float* g1r = &gt[1 * 256 + r * 16];
            const float* g2r = &gt[2 * 256 + r * 16];
            const float4 g2v = *(const float4*)(g2r + fcb);
            const float cb = g1r[eb] * s[r];
            const float4 coef = {g2v.x * cb, g2v.y * cb, g2v.z * cb, g2v.w * cb};
#pragma unroll
            for (int a = 0; a < 16; ++a) {
                const float g = g0r[a];
                acc[a].x += g * coef.x;
                acc[a].y += g * coef.y;
                acc[a].z += g * coef.z;
                acc[a].w += g * coef.w;
            }
        }

        // ---- epilogue: add bias, store coalesced float4 ----
        float* yn = out + (size_t)n * 4096;
#pragma unroll
        for (int a = 0; a < 16; ++a) {
            const float4 bv = *(const float4*)(&sb[a * 256 + lane * 4]);
            float4 o;
            o.x = acc[a].x + bv.x;
            o.y = acc[a].y + bv.y;
            o.z = acc[a].z + bv.z;
            o.w = acc[a].w + bv.w;
            *(float4*)(yn + a * 256 + lane * 4) = o;
        }
    }
}

extern "C" void kernel_launch(void* const* d_in, const int* in_sizes, int n_in,
                              void* d_out, int out_size, void* d_ws, size_t ws_size,
                              hipStream_t stream) {
    const float* x  = (const float*)d_in[0];
    const float* c0 = (const float*)d_in[1];
    const float* c1 = (const float*)d_in[2];
    const float* c2 = (const float*)d_in[3];
    const float* c3 = (const float*)d_in[4];
    const float* c4 = (const float*)d_in[5];
    const float* c5 = (const float*)d_in[6];
    const float* f0 = (const float*)d_in[7];
    const float* f1 = (const float*)d_in[8];
    const float* f2 = (const float*)d_in[9];
    const float* f3 = (const float*)d_in[10];
    const float* f4 = (const float*)d_in[11];
    const float* f5 = (const float*)d_in[12];
    const float* bias = (const float*)d_in[13];
    float* out = (float*)d_out;

    const int N = in_sizes[0] / 4096;
    const int grid = (N + WAVES_PER_BLOCK - 1) / WAVES_PER_BLOCK;

    kruskal_kernel<<<dim3(grid), dim3(256), 0, stream>>>(
        x, c0, c1, c2, c3, c4, c5, f0, f1, f2, f3, f4, f5, bias, out, N);
}

// Round 2
// 326.431 us; speedup vs baseline: 1.5206x; 1.5206x over previous
//
#include <hip/hip_runtime.h>

// KruskalLinearLayer: y[n,abc] = sum_r g0[a,r]g1[b,r]g2[c,r] * s[n,r] + bias
//   s[n,r] = sum_{d,e,f} g3[d,r]g4[e,r]g5[f,r] * x[n,def]
//   g_m = f_m @ c_m   (16x8 @ 8x16 = 16x16)
// One wave (64 lanes) per batch row. Lane owns 4 contiguous columns
// (ef = lane*4+j on input, bc = lane*4+j on output). Memory-bound:
// 128 MB total traffic -> ~20 us floor.
//
// R1 lesson: __launch_bounds__(256,4) capped VGPRs at 64 -> massive scratch
// spills (FETCH 465MB / WRITE 863MB vs 66/64 ideal). Now (256,2): VGPR cap
// 256, live set ~100. Phase 2 restructured: coef[16] precomputed (reuses
// dead xv regs), one float4 accumulator per 'a', immediate store.

#define WAVES_PER_BLOCK 4

__global__ __launch_bounds__(256, 2)
void kruskal_kernel(const float* __restrict__ x,
                    const float* __restrict__ c0, const float* __restrict__ c1,
                    const float* __restrict__ c2, const float* __restrict__ c3,
                    const float* __restrict__ c4, const float* __restrict__ c5,
                    const float* __restrict__ f0, const float* __restrict__ f1,
                    const float* __restrict__ f2, const float* __restrict__ f3,
                    const float* __restrict__ f4, const float* __restrict__ f5,
                    const float* __restrict__ bias,
                    float* __restrict__ out,
                    int N)
{
    // gt[m][r][idx] = g_m[idx][r]  (transposed: per-r rows contiguous)
    __shared__ __align__(16) float gt[6 * 256];
    __shared__ __align__(16) float g0n[256];    // g0 in [a][r] layout (float4-readable in r)
    __shared__ __align__(16) float sb[4096];    // bias staged in LDS

    const int tid = threadIdx.x;

    // ---- per-block precompute: g_m = f_m @ c_m into LDS ----
    {
        const float* F[6] = {f0, f1, f2, f3, f4, f5};
        const float* C[6] = {c0, c1, c2, c3, c4, c5};
        const int r = tid >> 4;   // 0..15
        const int a = tid & 15;   // 0..15
#pragma unroll
        for (int m = 0; m < 6; ++m) {
            const float* Fm = F[m];
            const float* Cm = C[m];
            float acc = 0.f;
#pragma unroll
            for (int k = 0; k < 8; ++k)
                acc += Fm[a * 8 + k] * Cm[k * 16 + r];
            gt[m * 256 + tid] = acc;            // gt[m][r][a]
            if (m == 0) g0n[a * 16 + r] = acc;  // g0[a][r]
        }
    }
#pragma unroll
    for (int t = 0; t < 16; ++t)
        sb[t * 256 + tid] = bias[t * 256 + tid];
    __syncthreads();

    const int lane   = tid & 63;
    const int waveId = tid >> 6;
    const int eb     = lane >> 2;        // e (phase 1) == b (phase 2)
    const int fcb    = (lane & 3) * 4;   // f base (phase 1) == c base (phase 2)

    const int totalWaves = gridDim.x * WAVES_PER_BLOCK;

    for (int n = blockIdx.x * WAVES_PER_BLOCK + waveId; n < N; n += totalWaves) {
        const float* xn = x + (size_t)n * 4096;

        // ---- load lane's 64 x values: x[d][ef], ef = lane*4 + j ----
        float4 xv[16];
#pragma unroll
        for (int d = 0; d < 16; ++d)
            xv[d] = *(const float4*)(xn + d * 256 + lane * 4);

        // ---- phase 1: per-lane partial s[r] ----
        float s[16];
#pragma unroll
        for (int r = 0; r < 16; ++r) {
            const float* g3r = &gt[3 * 256 + r * 16];
            const float* g4r = &gt[4 * 256 + r * 16];
            const float* g5r = &gt[5 * 256 + r * 16];
            float4 t = {0.f, 0.f, 0.f, 0.f};
#pragma unroll
            for (int d = 0; d < 16; ++d) {
                const float g = g3r[d];
                t.x += g * xv[d].x;
                t.y += g * xv[d].y;
                t.z += g * xv[d].z;
                t.w += g * xv[d].w;
            }
            const float4 g5v = *(const float4*)(g5r + fcb);
            const float p = t.x * g5v.x + t.y * g5v.y + t.z * g5v.z + t.w * g5v.w;
            s[r] = p * g4r[eb];
        }

        // ---- wave-wide reduction of each s[r] across 64 lanes ----
#pragma unroll
        for (int r = 0; r < 16; ++r) {
            float v = s[r];
            v += __shfl_xor(v, 1, 64);
            v += __shfl_xor(v, 2, 64);
            v += __shfl_xor(v, 4, 64);
            v += __shfl_xor(v, 8, 64);
            v += __shfl_xor(v, 16, 64);
            v += __shfl_xor(v, 32, 64);
            s[r] = v;
        }

        // ---- phase 2 prep: coef[r] = g2[c,r] * g1[b,r] * s[r] (xv regs now dead) ----
        float4 coef[16];
#pragma unroll
        for (int r = 0; r < 16; ++r) {
            const float4 g2v = *(const float4*)(&gt[2 * 256 + r * 16 + fcb]);
            const float  cb  = gt[1 * 256 + r * 16 + eb] * s[r];
            coef[r].x = g2v.x * cb;
            coef[r].y = g2v.y * cb;
            coef[r].z = g2v.z * cb;
            coef[r].w = g2v.w * cb;
        }

        // ---- phase 2: one 'a' at a time, single float4 accumulator, store now ----
        float* yn = out + (size_t)n * 4096;
#pragma unroll
        for (int a = 0; a < 16; ++a) {
            float4 acc = *(const float4*)(&sb[a * 256 + lane * 4]);  // init = bias
            const float4* g0a = (const float4*)(&g0n[a * 16]);
#pragma unroll
            for (int rq = 0; rq < 4; ++rq) {
                const float4 g = g0a[rq];   // broadcast LDS read (lane-uniform addr)
                const float4 c0v = coef[rq * 4 + 0];
                const float4 c1v = coef[rq * 4 + 1];
                const float4 c2v = coef[rq * 4 + 2];
                const float4 c3v = coef[rq * 4 + 3];
                acc.x += g.x * c0v.x + g.y * c1v.x + g.z * c2v.x + g.w * c3v.x;
                acc.y += g.x * c0v.y + g.y * c1v.y + g.z * c2v.y + g.w * c3v.y;
                acc.z += g.x * c0v.z + g.y * c1v.z + g.z * c2v.z + g.w * c3v.z;
                acc.w += g.x * c0v.w + g.y * c1v.w + g.z * c2v.w + g.w * c3v.w;
            }
            *(float4*)(yn + a * 256 + lane * 4) = acc;
        }
    }
}

extern "C" void kernel_launch(void* const* d_in, const int* in_sizes, int n_in,
                              void* d_out, int out_size, void* d_ws, size_t ws_size,
                              hipStream_t stream) {
    const float* x  = (const float*)d_in[0];
    const float* c0 = (const float*)d_in[1];
    const float* c1 = (const float*)d_in[2];
    const float* c2 = (const float*)d_in[3];
    const float* c3 = (const float*)d_in[4];
    const float* c4 = (const float*)d_in[5];
    const float* c5 = (const float*)d_in[6];
    const float* f0 = (const float*)d_in[7];
    const float* f1 = (const float*)d_in[8];
    const float* f2 = (const float*)d_in[9];
    const float* f3 = (const float*)d_in[10];
    const float* f4 = (const float*)d_in[11];
    const float* f5 = (const float*)d_in[12];
    const float* bias = (const float*)d_in[13];
    float* out = (float*)d_out;

    const int N = in_sizes[0] / 4096;
    const int grid = (N + WAVES_PER_BLOCK - 1) / WAVES_PER_BLOCK;

    kruskal_kernel<<<dim3(grid), dim3(256), 0, stream>>>(
        x, c0, c1, c2, c3, c4, c5, f0, f1, f2, f3, f4, f5, bias, out, N);
}

// Round 4
// 323.757 us; speedup vs baseline: 1.5332x; 1.0083x over previous
//
#include <hip/hip_runtime.h>

// KruskalLinearLayer: y[n,abc] = sum_r g0[a,r]g1[b,r]g2[c,r] * s[n,r] + bias
//   s[n,r] = sum_{d,e,f} g3[d,r]g4[e,r]g5[f,r] * x[n,def]
//   g_m = f_m @ c_m   (16x8 @ 8x16 = 16x16)
// One wave per batch row. Lane owns 4 contiguous cols (ef/bc = lane*4+j).
// Memory-bound: 128 MB minimum traffic -> ~20 us floor at 6.3 TB/s.
//
// R1: launch_bounds(256,4) -> 64-VGPR cap -> huge spills (1.36 GB traffic).
// R2: (256,2) -> VGPR 128, STILL spilled (773 MB): xv[16] float4 = 64 regs
//     live across whole r-loop pushed peak >128.
// R3: phase 1 split into two d-halves (xv[8] = 32 regs, scalar s[r] partial
//     per half) -> peak live ~85 regs. NT loads/stores keep the touch-once
//     x/y streams out of L2. (R3 compile fix: NT builtins need a native
//     ext_vector_type, not HIP_vector_type float4.)

typedef float f32x4 __attribute__((ext_vector_type(4)));

#define WAVES_PER_BLOCK 4

__global__ __launch_bounds__(256, 1)
void kruskal_kernel(const float* __restrict__ x,
                    const float* __restrict__ c0, const float* __restrict__ c1,
                    const float* __restrict__ c2, const float* __restrict__ c3,
                    const float* __restrict__ c4, const float* __restrict__ c5,
                    const float* __restrict__ f0, const float* __restrict__ f1,
                    const float* __restrict__ f2, const float* __restrict__ f3,
                    const float* __restrict__ f4, const float* __restrict__ f5,
                    const float* __restrict__ bias,
                    float* __restrict__ out,
                    int N)
{
    // gt[m][r][idx] = g_m[idx][r]  (transposed: per-r rows contiguous)
    __shared__ __align__(16) float gt[6 * 256];
    __shared__ __align__(16) float g0n[256];    // g0 in [a][r] layout
    __shared__ __align__(16) float sb[4096];    // bias staged in LDS

    const int tid = threadIdx.x;

    // ---- per-block precompute: g_m = f_m @ c_m into LDS ----
    {
        const float* F[6] = {f0, f1, f2, f3, f4, f5};
        const float* C[6] = {c0, c1, c2, c3, c4, c5};
        const int r = tid >> 4;   // 0..15
        const int a = tid & 15;   // 0..15
#pragma unroll
        for (int m = 0; m < 6; ++m) {
            const float* Fm = F[m];
            const float* Cm = C[m];
            float acc = 0.f;
#pragma unroll
            for (int k = 0; k < 8; ++k)
                acc += Fm[a * 8 + k] * Cm[k * 16 + r];
            gt[m * 256 + tid] = acc;            // gt[m][r][a]
            if (m == 0) g0n[a * 16 + r] = acc;  // g0[a][r]
        }
    }
#pragma unroll
    for (int t = 0; t < 16; ++t)
        sb[t * 256 + tid] = bias[t * 256 + tid];
    __syncthreads();

    const int lane   = tid & 63;
    const int waveId = tid >> 6;
    const int eb     = lane >> 2;        // e (phase 1) == b (phase 2)
    const int fcb    = (lane & 3) * 4;   // f base (phase 1) == c base (phase 2)

    const int totalWaves = gridDim.x * WAVES_PER_BLOCK;

    for (int n = blockIdx.x * WAVES_PER_BLOCK + waveId; n < N; n += totalWaves) {
        const float* xn = x + (size_t)n * 4096;

        // ---- phase 1 over two d-halves: s[r] = sum_d g3[d,r]*dot4(g5v[r], x[d]) ----
        float s[16];
        f32x4 xv[8];   // only 8 rows resident at a time (32 VGPRs)
#pragma unroll
        for (int h = 0; h < 2; ++h) {
#pragma unroll
            for (int dd = 0; dd < 8; ++dd)
                xv[dd] = __builtin_nontemporal_load(
                    (const f32x4*)(xn + (h * 8 + dd) * 256 + lane * 4));
#pragma unroll
            for (int r = 0; r < 16; ++r) {
                const float* g3r = &gt[3 * 256 + r * 16 + h * 8];
                f32x4 t = {0.f, 0.f, 0.f, 0.f};
#pragma unroll
                for (int dd = 0; dd < 8; ++dd) {
                    const float g = g3r[dd];
                    t += g * xv[dd];
                }
                const f32x4 g5v = *(const f32x4*)(&gt[5 * 256 + r * 16 + fcb]);
                const float p = t.x * g5v.x + t.y * g5v.y + t.z * g5v.z + t.w * g5v.w;
                s[r] = (h == 0) ? p : (s[r] + p);
            }
        }
#pragma unroll
        for (int r = 0; r < 16; ++r)
            s[r] *= gt[4 * 256 + r * 16 + eb];

        // ---- wave-wide reduction of each s[r] across 64 lanes ----
#pragma unroll
        for (int r = 0; r < 16; ++r) {
            float v = s[r];
            v += __shfl_xor(v, 1, 64);
            v += __shfl_xor(v, 2, 64);
            v += __shfl_xor(v, 4, 64);
            v += __shfl_xor(v, 8, 64);
            v += __shfl_xor(v, 16, 64);
            v += __shfl_xor(v, 32, 64);
            s[r] = v;
        }

        // ---- phase 2 prep: coef[r] = g2[c,r] * g1[b,r] * s[r] (xv regs dead) ----
        f32x4 coef[16];
#pragma unroll
        for (int r = 0; r < 16; ++r) {
            const f32x4 g2v = *(const f32x4*)(&gt[2 * 256 + r * 16 + fcb]);
            const float cb  = gt[1 * 256 + r * 16 + eb] * s[r];
            coef[r] = g2v * cb;
        }

        // ---- phase 2: one 'a' at a time, single f32x4 accumulator, store now ----
        float* yn = out + (size_t)n * 4096;
#pragma unroll
        for (int a = 0; a < 16; ++a) {
            f32x4 acc = *(const f32x4*)(&sb[a * 256 + lane * 4]);  // init = bias
            const f32x4* g0a = (const f32x4*)(&g0n[a * 16]);
#pragma unroll
            for (int rq = 0; rq < 4; ++rq) {
                const f32x4 g = g0a[rq];   // broadcast LDS read (lane-uniform)
                acc += g.x * coef[rq * 4 + 0];
                acc += g.y * coef[rq * 4 + 1];
                acc += g.z * coef[rq * 4 + 2];
                acc += g.w * coef[rq * 4 + 3];
            }
            __builtin_nontemporal_store(acc, (f32x4*)(yn + a * 256 + lane * 4));
        }
    }
}

extern "C" void kernel_launch(void* const* d_in, const int* in_sizes, int n_in,
                              void* d_out, int out_size, void* d_ws, size_t ws_size,
                              hipStream_t stream) {
    const float* x  = (const float*)d_in[0];
    const float* c0 = (const float*)d_in[1];
    const float* c1 = (const float*)d_in[2];
    const float* c2 = (const float*)d_in[3];
    const float* c3 = (const float*)d_in[4];
    const float* c4 = (const float*)d_in[5];
    const float* c5 = (const float*)d_in[6];
    const float* f0 = (const float*)d_in[7];
    const float* f1 = (const float*)d_in[8];
    const float* f2 = (const float*)d_in[9];
    const float* f3 = (const float*)d_in[10];
    const float* f4 = (const float*)d_in[11];
    const float* f5 = (const float*)d_in[12];
    const float* bias = (const float*)d_in[13];
    float* out = (float*)d_out;

    const int N = in_sizes[0] / 4096;
    const int grid = (N + WAVES_PER_BLOCK - 1) / WAVES_PER_BLOCK;

    kruskal_kernel<<<dim3(grid), dim3(256), 0, stream>>>(
        x, c0, c1, c2, c3, c4, c5, f0, f1, f2, f3, f4, f5, bias, out, N);
}